// Round 7
// baseline (281.547 us; speedup 1.0000x reference)
//
#include <hip/hip_runtime.h>

typedef short bf16x8 __attribute__((ext_vector_type(8)));
typedef short short8 __attribute__((ext_vector_type(8)));
typedef float f32x16 __attribute__((ext_vector_type(16)));

#define DD 512
#define NG 512

typedef __attribute__((address_space(3))) void lds_void;
typedef __attribute__((address_space(1))) void glb_void;

static __device__ __forceinline__ void gload_lds16(const void* g, void* l) {
  __builtin_amdgcn_global_load_lds((const glb_void*)g, (lds_void*)l, 16, 0, 0);
}

#define WAITV(n) asm volatile("s_waitcnt vmcnt(" #n ") lgkmcnt(0)" ::: "memory")
#define MEMFENCE asm volatile("" ::: "memory")

// split f32 into bf16 hi (truncate) + bf16 lo (round) ; f ≈ hi + lo, ~2^-16 rel err
static __device__ __forceinline__ void cvt_hl(float f, unsigned short& h, unsigned short& l) {
  unsigned u = __builtin_bit_cast(unsigned, f);
  unsigned hu = u & 0xffff0000u;
  float fh = __builtin_bit_cast(float, hu);
  float fl = f - fh;                       // exact in f32
  unsigned ul = __builtin_bit_cast(unsigned, fl);
  h = (unsigned short)(hu >> 16);
  l = (unsigned short)((ul + 0x8000u) >> 16);
}

// fast tanh: 1 - 2/(e^{2v}+1), native exp/rcp (~1e-6 abs err, saturates correctly)
static __device__ __forceinline__ float fast_tanh(float v) {
  float e = __expf(2.0f * v);
  return 1.0f - 2.0f * __builtin_amdgcn_rcpf(e + 1.0f);
}

// Whl layout: [ny(2)][kt(32)][ct(8)][hl(2)][lane(64)=khalf*32+c31][e(8 bf16)]
// One (ny,kt) slice = 16 KB contiguous -> staged linearly by global_load_lds.
// B-fragment ds_read is lds + lane*16 (+ct*2048 +hl*1024): 64 lanes read 1024
// contiguous bytes -> zero bank conflicts (verified round 4).
__global__ __launch_bounds__(256) void k_convert_w(const float* __restrict__ W,
                                                   unsigned char* __restrict__ Whl) {
  int t = blockIdx.x * 256 + threadIdx.x;   // 32768 = 512 W-rows x 64 kgroups(8)
  int r512 = t >> 6, kg = t & 63;
  int ny = r512 >> 8, col = r512 & 255;
  int ct = col >> 5, c31 = col & 31;
  int kt = kg >> 1, khalf = kg & 1;
  const float* p = W + (size_t)r512 * DD + kg * 8;
  short8 h, l;
#pragma unroll
  for (int j = 0; j < 8; ++j) {
    unsigned short hh, ll;
    cvt_hl(p[j], hh, ll);
    h[j] = (short)hh;
    l[j] = (short)ll;
  }
  unsigned char* dst = Whl + (size_t)ny * 524288 + (size_t)kt * 16384 +
                       ct * 2048 + (khalf * 32 + c31) * 16;
  *(short8*)dst = h;             // hi plane
  *(short8*)(dst + 1024) = l;    // lo plane
}

// Fused GEMM(tanh-gate) + query-dot.  Wave = 64 rows x 128 cols (2 row-frags x
// 4 ct tiles x 3 MFMAs, acc = 128 regs).  Block = 4 waves (2 rg x 2 cg) = 128
// rows x 256 cols (ny = col half).  B slices (16 KB) + A x-tiles (8 KB,
// sigma-swizzled chunks) staged via global_load_lds ring-3, counted vmcnt.
// Per wave per kt: 12 b128 ds_reads + 24 MFMA (LDS queue < MFMA pipe).
__global__ __launch_bounds__(256, 2) void k_gemm_score(
    const float* __restrict__ x, const unsigned char* __restrict__ Whl,
    const float* __restrict__ bias, const float* __restrict__ query,
    float* __restrict__ score_part, int N) {
  __shared__ unsigned char ldsB[3][16384];
  __shared__ unsigned char ldsA[3][8192];
  __shared__ float comb[2][128];
  const int tid = threadIdx.x;
  const int wave = tid >> 6;
  const int lane = tid & 63;
  const int l31 = lane & 31;
  const int kh = lane >> 5;          // k-half within fragment
  const int rg = wave >> 1;          // row-group (0,1): rows rg*64..rg*64+63
  const int cg = wave & 1;           // col-group (0,1): cts cg*4..cg*4+3
  const int ny = blockIdx.x;
  const int brow0 = blockIdx.y * 128;

  const unsigned char* wsrc = Whl + (size_t)ny * 524288 +
                              (size_t)wave * 4096 + (size_t)lane * 16;

  // A staging: 512 chunks of 16B per slice; LDS[c] <- x-data[sigma(c)],
  // sigma(c) = c ^ ((c>>3)&7) (involution, bits 0-2 only).  Chunk d of the
  // x-tile: row = d>>2 (block row), kq = d&3 (k-quad within the 16-k slice).
  const int c0 = wave * 128 + lane;
  const int c1 = c0 + 64;
  const int s0c = c0 ^ ((c0 >> 3) & 7);
  const int s1c = c1 ^ ((c1 >> 3) & 7);
  const float* asrc0 = x + (size_t)(brow0 + (s0c >> 2)) * DD + (s0c & 3) * 4;
  const float* asrc1 = x + (size_t)(brow0 + (s1c >> 2)) * DD + (s1c & 3) * 4;

  // A read offsets (bytes) for row-frags f=0,1: logical chunk u = row*4+2*kh
  int aoff[2][2];
#pragma unroll
  for (int f = 0; f < 2; ++f) {
    const int row = rg * 64 + f * 32 + l31;
    const int u = row * 4 + 2 * kh;
    const int m = (u >> 3) & 7;
    aoff[f][0] = (u ^ m) * 16;
    aoff[f][1] = ((u + 1) ^ m) * 16;
  }

  f32x16 acc[2][4];
#pragma unroll
  for (int f = 0; f < 2; ++f)
#pragma unroll
    for (int j = 0; j < 4; ++j)
#pragma unroll
      for (int r = 0; r < 16; ++r) acc[f][j][r] = 0.f;

  // prologue: stage slices 0 and 1 (6 gloads each per wave: 4 B + 2 A)
#pragma unroll
  for (int s = 0; s < 2; ++s) {
#pragma unroll
    for (int i = 0; i < 4; ++i)
      gload_lds16(wsrc + (size_t)s * 16384 + i * 1024, &ldsB[s][wave * 4096 + i * 1024]);
    gload_lds16(asrc0 + s * 16, &ldsA[s][wave * 2048]);
    gload_lds16(asrc1 + s * 16, &ldsA[s][wave * 2048 + 1024]);
    MEMFENCE;
  }

  for (int kt = 0; kt < 32; ++kt) {
    // slice kt's 6 gloads have exactly {kt+1}'s 6 newer -> vmcnt(6); tail drains.
    if (kt == 31) WAITV(0); else WAITV(6);
    __builtin_amdgcn_s_barrier();
    MEMFENCE;

    if (kt < 30) {  // stage slice kt+2 into slot (kt+2)%3 (readers of kt-1 done)
      const int s = (kt + 2) % 3;
      const unsigned char* src = wsrc + (size_t)(kt + 2) * 16384;
#pragma unroll
      for (int i = 0; i < 4; ++i)
        gload_lds16(src + i * 1024, &ldsB[s][wave * 4096 + i * 1024]);
      gload_lds16(asrc0 + (kt + 2) * 16, &ldsA[s][wave * 2048]);
      gload_lds16(asrc1 + (kt + 2) * 16, &ldsA[s][wave * 2048 + 1024]);
    }
    MEMFENCE;

    const int slot = kt % 3;
    const unsigned char* ab = &ldsA[slot][0];
    const unsigned char* bb = &ldsB[slot][lane * 16 + cg * 8192];

    // A fragments for both row-frags, converted to bf16 hi/lo
    bf16x8 ah[2], al[2];
#pragma unroll
    for (int f = 0; f < 2; ++f) {
      const float4 a0 = *(const float4*)(ab + aoff[f][0]);
      const float4 a1 = *(const float4*)(ab + aoff[f][1]);
      float af[8] = {a0.x, a0.y, a0.z, a0.w, a1.x, a1.y, a1.z, a1.w};
#pragma unroll
      for (int j = 0; j < 8; ++j) {
        unsigned short hh, ll;
        cvt_hl(af[j], hh, ll);
        ah[f][j] = (short)hh;
        al[f][j] = (short)ll;
      }
    }

    __builtin_amdgcn_s_setprio(1);
#pragma unroll
    for (int j = 0; j < 4; ++j) {
      bf16x8 bh = *(const bf16x8*)(bb + j * 2048);
      bf16x8 bl = *(const bf16x8*)(bb + j * 2048 + 1024);
#pragma unroll
      for (int f = 0; f < 2; ++f) {
        acc[f][j] = __builtin_amdgcn_mfma_f32_32x32x16_bf16(ah[f], bh, acc[f][j], 0, 0, 0);
        acc[f][j] = __builtin_amdgcn_mfma_f32_32x32x16_bf16(al[f], bh, acc[f][j], 0, 0, 0);
        acc[f][j] = __builtin_amdgcn_mfma_f32_32x32x16_bf16(ah[f], bl, acc[f][j], 0, 0, 0);
      }
    }
    __builtin_amdgcn_s_setprio(0);
  }

  // epilogue: tanh + query-dot; reduce over the 32 col-lanes; combine cg halves
  float sp[2][16];
#pragma unroll
  for (int f = 0; f < 2; ++f)
#pragma unroll
    for (int r = 0; r < 16; ++r) sp[f][r] = 0.f;
#pragma unroll
  for (int j = 0; j < 4; ++j) {
    const int col = ny * 256 + (cg * 4 + j) * 32 + l31;
    const float bb2 = bias[col];
    const float qq = query[col];
#pragma unroll
    for (int f = 0; f < 2; ++f)
#pragma unroll
      for (int r = 0; r < 16; ++r)
        sp[f][r] += fast_tanh(acc[f][j][r] + bb2) * qq;
  }
#pragma unroll
  for (int f = 0; f < 2; ++f)
#pragma unroll
    for (int r = 0; r < 16; ++r) {
      float v = sp[f][r];
      v += __shfl_xor(v, 1);
      v += __shfl_xor(v, 2);
      v += __shfl_xor(v, 4);
      v += __shfl_xor(v, 8);
      v += __shfl_xor(v, 16);
      if (l31 == 0)  // C row = (r&3) + 8*(r>>2) + 4*kh  (m74/m101 layout)
        comb[cg][rg * 64 + f * 32 + (r & 3) + 8 * (r >> 2) + 4 * kh] = v;
    }
  __syncthreads();
  if (tid < 128)
    score_part[(size_t)ny * N + brow0 + tid] = comb[0][tid] + comb[1][tid];
}

// Per-graph: segmented softmax over (sp0+sp1) + weighted sum of x rows -> out[g][512]
__global__ __launch_bounds__(256) void k_softmax_out(
    const float* __restrict__ x, const void* __restrict__ segp,
    const float* __restrict__ sp0, const float* __restrict__ sp1,
    float* __restrict__ out, int N) {
  const int g = blockIdx.x;
  const int tid = threadIdx.x;

  // dtype probe: int64 element N/2-1 is a graph id (<NG) iff buffer is int64.
  const long long probe = ((const long long*)segp)[N / 2 - 1];
  const bool is64 = ((unsigned long long)probe < (unsigned long long)NG);
  const long long* s64 = (const long long*)segp;
  const int* s32 = (const int*)segp;

  int s0, s1;
  {
    int lo = 0, hi = N;
    while (lo < hi) {
      int m = (lo + hi) >> 1;
      long long v = is64 ? s64[m] : (long long)s32[m];
      if (v < (long long)g) lo = m + 1; else hi = m;
    }
    s0 = lo;
    lo = s0; hi = N;
    while (lo < hi) {
      int m = (lo + hi) >> 1;
      long long v = is64 ? s64[m] : (long long)s32[m];
      if (v < (long long)(g + 1)) lo = m + 1; else hi = m;
    }
    s1 = lo;
  }

  __shared__ float red[4];
  __shared__ float wbuf[512];

  float lm = -INFINITY;
  for (int i = s0 + tid; i < s1; i += 256) lm = fmaxf(lm, sp0[i] + sp1[i]);
#pragma unroll
  for (int m = 1; m < 64; m <<= 1) lm = fmaxf(lm, __shfl_xor(lm, m));
  if ((tid & 63) == 0) red[tid >> 6] = lm;
  __syncthreads();
  const float mx = fmaxf(fmaxf(red[0], red[1]), fmaxf(red[2], red[3]));
  __syncthreads();

  float ls = 0.f;
  for (int i = s0 + tid; i < s1; i += 256) ls += expf(sp0[i] + sp1[i] - mx);
#pragma unroll
  for (int m = 1; m < 64; m <<= 1) ls += __shfl_xor(ls, m);
  if ((tid & 63) == 0) red[tid >> 6] = ls;
  __syncthreads();
  const float sum = red[0] + red[1] + red[2] + red[3];
  const float inv = sum > 0.f ? 1.0f / sum : 0.f;

  float a0 = 0.f, a1 = 0.f;
  const int c = tid * 2;
  for (int base = s0; base < s1; base += 512) {
    const int cnt = min(512, s1 - base);
    __syncthreads();
    for (int i = tid; i < cnt; i += 256)
      wbuf[i] = expf(sp0[base + i] + sp1[base + i] - mx) * inv;
    __syncthreads();
#pragma unroll 4
    for (int j = 0; j < cnt; ++j) {
      const float w = wbuf[j];
      const float2 xv = *(const float2*)(x + (size_t)(base + j) * DD + c);
      a0 = fmaf(w, xv.x, a0);
      a1 = fmaf(w, xv.y, a1);
    }
  }
  float* op = out + (size_t)g * DD + c;
  op[0] = a0;
  op[1] = a1;
}

extern "C" void kernel_launch(void* const* d_in, const int* in_sizes, int n_in,
                              void* d_out, int out_size, void* d_ws, size_t ws_size,
                              hipStream_t stream) {
  const float* x = (const float*)d_in[0];
  const void* seg = d_in[1];
  const float* W = (const float*)d_in[2];
  const float* b = (const float*)d_in[3];
  const float* q = (const float*)d_in[4];
  float* out = (float*)d_out;
  const int N = in_sizes[0] / DD;  // 131072

  unsigned char* Whl = (unsigned char*)d_ws;                 // 1 MB packed W (hi/lo)
  float* sp0 = (float*)(Whl + 1048576);                      // N partial scores (ny=0)
  float* sp1 = sp0 + N;                                      // N partial scores (ny=1)

  k_convert_w<<<128, 256, 0, stream>>>(W, Whl);
  dim3 grid(2, N / 128);                                     // x = ny fastest -> x-row cache reuse
  k_gemm_score<<<grid, 256, 0, stream>>>(x, Whl, b, q, sp0, N);
  k_softmax_out<<<NG, 256, 0, stream>>>(x, seg, sp0, sp1, out, N);
}

// Round 8
// 245.977 us; speedup vs baseline: 1.1446x; 1.1446x over previous
//
#include <hip/hip_runtime.h>

typedef _Float16 f16x8 __attribute__((ext_vector_type(8)));
typedef short short8 __attribute__((ext_vector_type(8)));
typedef float f32x16 __attribute__((ext_vector_type(16)));

#define DD 512
#define NG 512

typedef __attribute__((address_space(3))) void lds_void;
typedef __attribute__((address_space(1))) void glb_void;

static __device__ __forceinline__ void gload_lds16(const void* g, void* l) {
  __builtin_amdgcn_global_load_lds((const glb_void*)g, (lds_void*)l, 16, 0, 0);
}

#define WAITV(n) asm volatile("s_waitcnt vmcnt(" #n ") lgkmcnt(0)" ::: "memory")
#define MEMFENCE asm volatile("" ::: "memory")

// fast tanh: 1 - 2/(e^{2v}+1), native exp/rcp (~1e-6 abs err, saturates correctly)
static __device__ __forceinline__ float fast_tanh(float v) {
  float e = __expf(2.0f * v);
  return 1.0f - 2.0f * __builtin_amdgcn_rcpf(e + 1.0f);
}

// W f32 -> f16 hi + scaled f16 residual:  w ≈ hi + lo*2^-11  (rel err ~2^-22).
// Scaling the residual by 2^11 keeps it in f16-normal range (no denorm flush).
static __device__ __forceinline__ void cvt_w_hl(float w, unsigned short& h, unsigned short& l) {
  _Float16 hh = (_Float16)w;                       // v_cvt_f16_f32, RTE
  _Float16 ll = (_Float16)((w - (float)hh) * 2048.0f);
  h = __builtin_bit_cast(unsigned short, hh);
  l = __builtin_bit_cast(unsigned short, ll);
}

// Whl layout: [ny(2)][kt(32)][ct(8)][hl(2)][lane(64)=khalf*32+c31][e(8 f16)]
// One (ny,kt) slice = 16 KB contiguous -> staged linearly by global_load_lds.
// B-fragment ds_read is lds + lane*16 (+ct*2048 +hl*1024): 64 lanes read 1024
// contiguous bytes -> zero bank conflicts (verified round 4).
__global__ __launch_bounds__(256) void k_convert_w(const float* __restrict__ W,
                                                   unsigned char* __restrict__ Whl) {
  int t = blockIdx.x * 256 + threadIdx.x;   // 32768 = 512 W-rows x 64 kgroups(8)
  int r512 = t >> 6, kg = t & 63;
  int ny = r512 >> 8, col = r512 & 255;
  int ct = col >> 5, c31 = col & 31;
  int kt = kg >> 1, khalf = kg & 1;
  const float* p = W + (size_t)r512 * DD + kg * 8;
  short8 h, l;
#pragma unroll
  for (int j = 0; j < 8; ++j) {
    unsigned short hh, ll;
    cvt_w_hl(p[j], hh, ll);
    h[j] = (short)hh;
    l[j] = (short)ll;
  }
  unsigned char* dst = Whl + (size_t)ny * 524288 + (size_t)kt * 16384 +
                       ct * 2048 + (khalf * 32 + c31) * 16;
  *(short8*)dst = h;             // hi plane
  *(short8*)(dst + 1024) = l;    // scaled-lo plane
}

// Fused GEMM(tanh-gate) + query-dot.  Wave = 64 rows x 128 cols (2 row-frags x
// 4 ct tiles x 2 MFMAs: ah*bh + a2*bl, acc = 128 regs).  Block = 4 waves
// (2 rg x 2 cg) = 128 rows x 256 cols (ny = col half).  B slices (16 KB) +
// A x-tiles (8 KB f32, sigma-swizzled chunks) staged via global_load_lds
// ring-3, counted vmcnt (structure verified rounds 6-7).
__global__ __launch_bounds__(256, 2) void k_gemm_score(
    const float* __restrict__ x, const unsigned char* __restrict__ Whl,
    const float* __restrict__ bias, const float* __restrict__ query,
    float* __restrict__ score_part, int N) {
  __shared__ unsigned char ldsB[3][16384];
  __shared__ unsigned char ldsA[3][8192];
  __shared__ float comb[2][128];
  const int tid = threadIdx.x;
  const int wave = tid >> 6;
  const int lane = tid & 63;
  const int l31 = lane & 31;
  const int kh = lane >> 5;          // k-half within fragment
  const int rg = wave >> 1;          // row-group (0,1): rows rg*64..rg*64+63
  const int cg = wave & 1;           // col-group (0,1): cts cg*4..cg*4+3
  const int ny = blockIdx.x;
  const int brow0 = blockIdx.y * 128;

  const unsigned char* wsrc = Whl + (size_t)ny * 524288 +
                              (size_t)wave * 4096 + (size_t)lane * 16;

  // A staging: 512 chunks of 16B per slice; LDS[c] <- x-data[sigma(c)],
  // sigma(c) = c ^ ((c>>3)&7) (involution).  Chunk d: row = d>>2, kq = d&3.
  const int c0 = wave * 128 + lane;
  const int c1 = c0 + 64;
  const int s0c = c0 ^ ((c0 >> 3) & 7);
  const int s1c = c1 ^ ((c1 >> 3) & 7);
  const float* asrc0 = x + (size_t)(brow0 + (s0c >> 2)) * DD + (s0c & 3) * 4;
  const float* asrc1 = x + (size_t)(brow0 + (s1c >> 2)) * DD + (s1c & 3) * 4;

  // A read offsets (bytes) for row-frags f=0,1: logical chunk u = row*4+2*kh
  int aoff[2][2];
#pragma unroll
  for (int f = 0; f < 2; ++f) {
    const int row = rg * 64 + f * 32 + l31;
    const int u = row * 4 + 2 * kh;
    const int m = (u >> 3) & 7;
    aoff[f][0] = (u ^ m) * 16;
    aoff[f][1] = ((u + 1) ^ m) * 16;
  }

  f32x16 acc[2][4];
#pragma unroll
  for (int f = 0; f < 2; ++f)
#pragma unroll
    for (int j = 0; j < 4; ++j)
#pragma unroll
      for (int r = 0; r < 16; ++r) acc[f][j][r] = 0.f;

  // prologue: stage slices 0 and 1 (6 gloads each per wave: 4 B + 2 A)
#pragma unroll
  for (int s = 0; s < 2; ++s) {
#pragma unroll
    for (int i = 0; i < 4; ++i)
      gload_lds16(wsrc + (size_t)s * 16384 + i * 1024, &ldsB[s][wave * 4096 + i * 1024]);
    gload_lds16(asrc0 + s * 16, &ldsA[s][wave * 2048]);
    gload_lds16(asrc1 + s * 16, &ldsA[s][wave * 2048 + 1024]);
    MEMFENCE;
  }

  for (int kt = 0; kt < 32; ++kt) {
    // slice kt's 6 gloads have exactly {kt+1}'s 6 newer -> vmcnt(6); tail drains.
    if (kt == 31) WAITV(0); else WAITV(6);
    __builtin_amdgcn_s_barrier();
    MEMFENCE;

    if (kt < 30) {  // stage slice kt+2 into slot (kt+2)%3 (readers of kt-1 done)
      const int s = (kt + 2) % 3;
      const unsigned char* src = wsrc + (size_t)(kt + 2) * 16384;
#pragma unroll
      for (int i = 0; i < 4; ++i)
        gload_lds16(src + i * 1024, &ldsB[s][wave * 4096 + i * 1024]);
      gload_lds16(asrc0 + (kt + 2) * 16, &ldsA[s][wave * 2048]);
      gload_lds16(asrc1 + (kt + 2) * 16, &ldsA[s][wave * 2048 + 1024]);
    }
    MEMFENCE;

    const int slot = kt % 3;
    const unsigned char* ab = &ldsA[slot][0];
    const unsigned char* bb = &ldsB[slot][lane * 16 + cg * 8192];

    // A fragments: ah = f16(x), a2 = f16(x * 2^-11)  (pairs with scaled-lo B)
    f16x8 ah[2], a2[2];
#pragma unroll
    for (int f = 0; f < 2; ++f) {
      const float4 a0 = *(const float4*)(ab + aoff[f][0]);
      const float4 a1 = *(const float4*)(ab + aoff[f][1]);
      float af[8] = {a0.x, a0.y, a0.z, a0.w, a1.x, a1.y, a1.z, a1.w};
#pragma unroll
      for (int j = 0; j < 8; ++j) {
        ah[f][j] = (_Float16)af[j];
        a2[f][j] = (_Float16)(af[j] * 4.8828125e-4f);   // x * 2^-11
      }
    }

    __builtin_amdgcn_s_setprio(1);
#pragma unroll
    for (int j = 0; j < 4; ++j) {
      f16x8 bh = *(const f16x8*)(bb + j * 2048);
      f16x8 bl = *(const f16x8*)(bb + j * 2048 + 1024);
#pragma unroll
      for (int f = 0; f < 2; ++f) {
        acc[f][j] = __builtin_amdgcn_mfma_f32_32x32x16_f16(ah[f], bh, acc[f][j], 0, 0, 0);
        acc[f][j] = __builtin_amdgcn_mfma_f32_32x32x16_f16(a2[f], bl, acc[f][j], 0, 0, 0);
      }
    }
    __builtin_amdgcn_s_setprio(0);
  }

  // epilogue: tanh + query-dot; reduce over the 32 col-lanes; combine cg halves
  float sp[2][16];
#pragma unroll
  for (int f = 0; f < 2; ++f)
#pragma unroll
    for (int r = 0; r < 16; ++r) sp[f][r] = 0.f;
#pragma unroll
  for (int j = 0; j < 4; ++j) {
    const int col = ny * 256 + (cg * 4 + j) * 32 + l31;
    const float bb2 = bias[col];
    const float qq = query[col];
#pragma unroll
    for (int f = 0; f < 2; ++f)
#pragma unroll
      for (int r = 0; r < 16; ++r)
        sp[f][r] += fast_tanh(acc[f][j][r] + bb2) * qq;
  }
#pragma unroll
  for (int f = 0; f < 2; ++f)
#pragma unroll
    for (int r = 0; r < 16; ++r) {
      float v = sp[f][r];
      v += __shfl_xor(v, 1);
      v += __shfl_xor(v, 2);
      v += __shfl_xor(v, 4);
      v += __shfl_xor(v, 8);
      v += __shfl_xor(v, 16);
      if (l31 == 0)  // C row = (r&3) + 8*(r>>2) + 4*kh  (m74/m101 layout)
        comb[cg][rg * 64 + f * 32 + (r & 3) + 8 * (r >> 2) + 4 * kh] = v;
    }
  __syncthreads();
  if (tid < 128)
    score_part[(size_t)ny * N + brow0 + tid] = comb[0][tid] + comb[1][tid];
}

// Per-graph: segmented softmax over (sp0+sp1) + weighted sum of x rows -> out[g][512]
__global__ __launch_bounds__(256) void k_softmax_out(
    const float* __restrict__ x, const void* __restrict__ segp,
    const float* __restrict__ sp0, const float* __restrict__ sp1,
    float* __restrict__ out, int N) {
  const int g = blockIdx.x;
  const int tid = threadIdx.x;

  // dtype probe: int64 element N/2-1 is a graph id (<NG) iff buffer is int64.
  const long long probe = ((const long long*)segp)[N / 2 - 1];
  const bool is64 = ((unsigned long long)probe < (unsigned long long)NG);
  const long long* s64 = (const long long*)segp;
  const int* s32 = (const int*)segp;

  int s0, s1;
  {
    int lo = 0, hi = N;
    while (lo < hi) {
      int m = (lo + hi) >> 1;
      long long v = is64 ? s64[m] : (long long)s32[m];
      if (v < (long long)g) lo = m + 1; else hi = m;
    }
    s0 = lo;
    lo = s0; hi = N;
    while (lo < hi) {
      int m = (lo + hi) >> 1;
      long long v = is64 ? s64[m] : (long long)s32[m];
      if (v < (long long)(g + 1)) lo = m + 1; else hi = m;
    }
    s1 = lo;
  }

  __shared__ float red[4];
  __shared__ float wbuf[512];

  float lm = -INFINITY;
  for (int i = s0 + tid; i < s1; i += 256) lm = fmaxf(lm, sp0[i] + sp1[i]);
#pragma unroll
  for (int m = 1; m < 64; m <<= 1) lm = fmaxf(lm, __shfl_xor(lm, m));
  if ((tid & 63) == 0) red[tid >> 6] = lm;
  __syncthreads();
  const float mx = fmaxf(fmaxf(red[0], red[1]), fmaxf(red[2], red[3]));
  __syncthreads();

  float ls = 0.f;
  for (int i = s0 + tid; i < s1; i += 256) ls += expf(sp0[i] + sp1[i] - mx);
#pragma unroll
  for (int m = 1; m < 64; m <<= 1) ls += __shfl_xor(ls, m);
  if ((tid & 63) == 0) red[tid >> 6] = ls;
  __syncthreads();
  const float sum = red[0] + red[1] + red[2] + red[3];
  const float inv = sum > 0.f ? 1.0f / sum : 0.f;

  float a0 = 0.f, a1 = 0.f;
  const int c = tid * 2;
  for (int base = s0; base < s1; base += 512) {
    const int cnt = min(512, s1 - base);
    __syncthreads();
    for (int i = tid; i < cnt; i += 256)
      wbuf[i] = expf(sp0[base + i] + sp1[base + i] - mx) * inv;
    __syncthreads();
#pragma unroll 4
    for (int j = 0; j < cnt; ++j) {
      const float w = wbuf[j];
      const float2 xv = *(const float2*)(x + (size_t)(base + j) * DD + c);
      a0 = fmaf(w, xv.x, a0);
      a1 = fmaf(w, xv.y, a1);
    }
  }
  float* op = out + (size_t)g * DD + c;
  op[0] = a0;
  op[1] = a1;
}

extern "C" void kernel_launch(void* const* d_in, const int* in_sizes, int n_in,
                              void* d_out, int out_size, void* d_ws, size_t ws_size,
                              hipStream_t stream) {
  const float* x = (const float*)d_in[0];
  const void* seg = d_in[1];
  const float* W = (const float*)d_in[2];
  const float* b = (const float*)d_in[3];
  const float* q = (const float*)d_in[4];
  float* out = (float*)d_out;
  const int N = in_sizes[0] / DD;  // 131072

  unsigned char* Whl = (unsigned char*)d_ws;                 // 1 MB packed W (f16 hi/lo)
  float* sp0 = (float*)(Whl + 1048576);                      // N partial scores (ny=0)
  float* sp1 = sp0 + N;                                      // N partial scores (ny=1)

  k_convert_w<<<128, 256, 0, stream>>>(W, Whl);
  dim3 grid(2, N / 128);                                     // x = ny fastest -> x-row cache reuse
  k_gemm_score<<<grid, 256, 0, stream>>>(x, Whl, b, q, sp0, N);
  k_softmax_out<<<NG, 256, 0, stream>>>(x, seg, sp0, sp1, out, N);
}

// Round 9
// 183.911 us; speedup vs baseline: 1.5309x; 1.3375x over previous
//
#include <hip/hip_runtime.h>

typedef _Float16 f16x8 __attribute__((ext_vector_type(8)));
typedef short short8 __attribute__((ext_vector_type(8)));
typedef float f32x16 __attribute__((ext_vector_type(16)));

#define DD 512
#define NG 512

typedef __attribute__((address_space(3))) void lds_void;
typedef __attribute__((address_space(1))) void glb_void;

static __device__ __forceinline__ void gload_lds16(const void* g, void* l) {
  __builtin_amdgcn_global_load_lds((const glb_void*)g, (lds_void*)l, 16, 0, 0);
}

#define WAITV(n) asm volatile("s_waitcnt vmcnt(" #n ") lgkmcnt(0)" ::: "memory")
#define MEMFENCE asm volatile("" ::: "memory")

// fast tanh: 1 - 2/(e^{2v}+1), native exp/rcp (~1e-6 abs err, saturates correctly)
static __device__ __forceinline__ float fast_tanh(float v) {
  float e = __expf(2.0f * v);
  return 1.0f - 2.0f * __builtin_amdgcn_rcpf(e + 1.0f);
}

// Whl layout (f16 hi only): [ny(2)][kt(32)][ct(8)][lane(64)=khalf*32+c31][8 f16]
// One (ny,kt) slice = 8 KB contiguous -> staged linearly by global_load_lds.
// B-fragment ds_read is lds + lane*16 (+ct*1024): 64 lanes read 1024
// contiguous bytes -> zero bank conflicts (layout family verified round 4).
__global__ __launch_bounds__(256) void k_convert_w(const float* __restrict__ W,
                                                   unsigned char* __restrict__ Whl) {
  int t = blockIdx.x * 256 + threadIdx.x;   // 32768 = 512 W-rows x 64 kgroups(8)
  int r512 = t >> 6, kg = t & 63;
  int ny = r512 >> 8, col = r512 & 255;
  int ct = col >> 5, c31 = col & 31;
  int kt = kg >> 1, khalf = kg & 1;
  const float* p = W + (size_t)r512 * DD + kg * 8;
  short8 h;
#pragma unroll
  for (int j = 0; j < 8; ++j) {
    _Float16 hh = (_Float16)p[j];              // RTE
    h[j] = (short)__builtin_bit_cast(unsigned short, hh);
  }
  unsigned char* dst = Whl + (size_t)ny * 262144 + (size_t)kt * 8192 +
                       ct * 1024 + (khalf * 32 + c31) * 16;
  *(short8*)dst = h;
}

// Fused GEMM(tanh-gate) + query-dot.  Wave = 64 rows x 128 cols (2 row-frags x
// 4 ct tiles x 1 f16 MFMA, acc = 128 regs).  Block = 4 waves (2 rg x 2 cg) =
// 128 rows x 256 cols (ny = col half).  B slices (8 KB f16) + A x-tiles (8 KB
// f32, sigma-swizzled chunks) staged via global_load_lds ring-3, counted
// vmcnt (structure verified rounds 6-8).  49 KB LDS -> 3 blocks/CU.
__global__ __launch_bounds__(256, 3) void k_gemm_score(
    const float* __restrict__ x, const unsigned char* __restrict__ Whl,
    const float* __restrict__ bias, const float* __restrict__ query,
    float* __restrict__ score_part, int N) {
  __shared__ unsigned char ldsB[3][8192];
  __shared__ unsigned char ldsA[3][8192];
  __shared__ float comb[2][128];
  const int tid = threadIdx.x;
  const int wave = tid >> 6;
  const int lane = tid & 63;
  const int l31 = lane & 31;
  const int kh = lane >> 5;          // k-half within fragment
  const int rg = wave >> 1;          // row-group (0,1): rows rg*64..rg*64+63
  const int cg = wave & 1;           // col-group (0,1): cts cg*4..cg*4+3
  const int ny = blockIdx.x;
  const int brow0 = blockIdx.y * 128;

  const unsigned char* wsrc = Whl + (size_t)ny * 262144 +
                              (size_t)wave * 2048 + (size_t)lane * 16;

  // A staging: 512 chunks of 16B per slice; LDS[c] <- x-data[sigma(c)],
  // sigma(c) = c ^ ((c>>3)&7) (involution).  Chunk d: row = d>>2, kq = d&3.
  const int c0 = wave * 128 + lane;
  const int c1 = c0 + 64;
  const int s0c = c0 ^ ((c0 >> 3) & 7);
  const int s1c = c1 ^ ((c1 >> 3) & 7);
  const float* asrc0 = x + (size_t)(brow0 + (s0c >> 2)) * DD + (s0c & 3) * 4;
  const float* asrc1 = x + (size_t)(brow0 + (s1c >> 2)) * DD + (s1c & 3) * 4;

  // A read offsets (bytes) for row-frags f=0,1: logical chunk u = row*4+2*kh
  int aoff[2][2];
#pragma unroll
  for (int f = 0; f < 2; ++f) {
    const int row = rg * 64 + f * 32 + l31;
    const int u = row * 4 + 2 * kh;
    const int m = (u >> 3) & 7;
    aoff[f][0] = (u ^ m) * 16;
    aoff[f][1] = ((u + 1) ^ m) * 16;
  }

  f32x16 acc[2][4];
#pragma unroll
  for (int f = 0; f < 2; ++f)
#pragma unroll
    for (int j = 0; j < 4; ++j)
#pragma unroll
      for (int r = 0; r < 16; ++r) acc[f][j][r] = 0.f;

  // prologue: stage slices 0 and 1 (4 gloads each per wave: 2 B + 2 A)
#pragma unroll
  for (int s = 0; s < 2; ++s) {
#pragma unroll
    for (int i = 0; i < 2; ++i)
      gload_lds16(wsrc + (size_t)s * 8192 + i * 1024, &ldsB[s][wave * 2048 + i * 1024]);
    gload_lds16(asrc0 + s * 16, &ldsA[s][wave * 2048]);
    gload_lds16(asrc1 + s * 16, &ldsA[s][wave * 2048 + 1024]);
    MEMFENCE;
  }

  for (int kt = 0; kt < 32; ++kt) {
    // slice kt's 4 gloads have exactly {kt+1}'s 4 newer -> vmcnt(4); tail drains.
    if (kt == 31) WAITV(0); else WAITV(4);
    __builtin_amdgcn_s_barrier();
    MEMFENCE;

    if (kt < 30) {  // stage slice kt+2 into slot (kt+2)%3 (readers of kt-1 done)
      const int s = (kt + 2) % 3;
      const unsigned char* src = wsrc + (size_t)(kt + 2) * 8192;
#pragma unroll
      for (int i = 0; i < 2; ++i)
        gload_lds16(src + i * 1024, &ldsB[s][wave * 2048 + i * 1024]);
      gload_lds16(asrc0 + (kt + 2) * 16, &ldsA[s][wave * 2048]);
      gload_lds16(asrc1 + (kt + 2) * 16, &ldsA[s][wave * 2048 + 1024]);
    }
    MEMFENCE;

    const int slot = kt % 3;
    const unsigned char* ab = &ldsA[slot][0];
    const unsigned char* bb = &ldsB[slot][lane * 16 + cg * 4096];

    // A fragments: ah = f16(x)  (single-plane scheme)
    f16x8 ah[2];
#pragma unroll
    for (int f = 0; f < 2; ++f) {
      const float4 a0 = *(const float4*)(ab + aoff[f][0]);
      const float4 a1 = *(const float4*)(ab + aoff[f][1]);
      float af[8] = {a0.x, a0.y, a0.z, a0.w, a1.x, a1.y, a1.z, a1.w};
#pragma unroll
      for (int j = 0; j < 8; ++j) ah[f][j] = (_Float16)af[j];
    }

    __builtin_amdgcn_s_setprio(1);
#pragma unroll
    for (int j = 0; j < 4; ++j) {
      f16x8 bh = *(const f16x8*)(bb + j * 1024);
#pragma unroll
      for (int f = 0; f < 2; ++f)
        acc[f][j] = __builtin_amdgcn_mfma_f32_32x32x16_f16(ah[f], bh, acc[f][j], 0, 0, 0);
    }
    __builtin_amdgcn_s_setprio(0);
  }

  // epilogue: tanh + query-dot; reduce over the 32 col-lanes; combine cg halves
  float sp[2][16];
#pragma unroll
  for (int f = 0; f < 2; ++f)
#pragma unroll
    for (int r = 0; r < 16; ++r) sp[f][r] = 0.f;
#pragma unroll
  for (int j = 0; j < 4; ++j) {
    const int col = ny * 256 + (cg * 4 + j) * 32 + l31;
    const float bb2 = bias[col];
    const float qq = query[col];
#pragma unroll
    for (int f = 0; f < 2; ++f)
#pragma unroll
      for (int r = 0; r < 16; ++r)
        sp[f][r] += fast_tanh(acc[f][j][r] + bb2) * qq;
  }
#pragma unroll
  for (int f = 0; f < 2; ++f)
#pragma unroll
    for (int r = 0; r < 16; ++r) {
      float v = sp[f][r];
      v += __shfl_xor(v, 1);
      v += __shfl_xor(v, 2);
      v += __shfl_xor(v, 4);
      v += __shfl_xor(v, 8);
      v += __shfl_xor(v, 16);
      if (l31 == 0)  // C row = (r&3) + 8*(r>>2) + 4*kh  (m74/m101 layout)
        comb[cg][rg * 64 + f * 32 + (r & 3) + 8 * (r >> 2) + 4 * kh] = v;
    }
  __syncthreads();
  if (tid < 128)
    score_part[(size_t)ny * N + brow0 + tid] = comb[0][tid] + comb[1][tid];
}

// Per-graph: segmented softmax over (sp0+sp1) + weighted sum of x rows -> out[g][512]
__global__ __launch_bounds__(256) void k_softmax_out(
    const float* __restrict__ x, const void* __restrict__ segp,
    const float* __restrict__ sp0, const float* __restrict__ sp1,
    float* __restrict__ out, int N) {
  const int g = blockIdx.x;
  const int tid = threadIdx.x;

  // dtype probe: int64 element N/2-1 is a graph id (<NG) iff buffer is int64.
  const long long probe = ((const long long*)segp)[N / 2 - 1];
  const bool is64 = ((unsigned long long)probe < (unsigned long long)NG);
  const long long* s64 = (const long long*)segp;
  const int* s32 = (const int*)segp;

  int s0, s1;
  {
    int lo = 0, hi = N;
    while (lo < hi) {
      int m = (lo + hi) >> 1;
      long long v = is64 ? s64[m] : (long long)s32[m];
      if (v < (long long)g) lo = m + 1; else hi = m;
    }
    s0 = lo;
    lo = s0; hi = N;
    while (lo < hi) {
      int m = (lo + hi) >> 1;
      long long v = is64 ? s64[m] : (long long)s32[m];
      if (v < (long long)(g + 1)) lo = m + 1; else hi = m;
    }
    s1 = lo;
  }

  __shared__ float red[4];
  __shared__ float wbuf[512];

  float lm = -INFINITY;
  for (int i = s0 + tid; i < s1; i += 256) lm = fmaxf(lm, sp0[i] + sp1[i]);
#pragma unroll
  for (int m = 1; m < 64; m <<= 1) lm = fmaxf(lm, __shfl_xor(lm, m));
  if ((tid & 63) == 0) red[tid >> 6] = lm;
  __syncthreads();
  const float mx = fmaxf(fmaxf(red[0], red[1]), fmaxf(red[2], red[3]));
  __syncthreads();

  float ls = 0.f;
  for (int i = s0 + tid; i < s1; i += 256) ls += expf(sp0[i] + sp1[i] - mx);
#pragma unroll
  for (int m = 1; m < 64; m <<= 1) ls += __shfl_xor(ls, m);
  if ((tid & 63) == 0) red[tid >> 6] = ls;
  __syncthreads();
  const float sum = red[0] + red[1] + red[2] + red[3];
  const float inv = sum > 0.f ? 1.0f / sum : 0.f;

  float a0 = 0.f, a1 = 0.f;
  const int c = tid * 2;
  for (int base = s0; base < s1; base += 512) {
    const int cnt = min(512, s1 - base);
    __syncthreads();
    for (int i = tid; i < cnt; i += 256)
      wbuf[i] = expf(sp0[base + i] + sp1[base + i] - mx) * inv;
    __syncthreads();
#pragma unroll 4
    for (int j = 0; j < cnt; ++j) {
      const float w = wbuf[j];
      const float2 xv = *(const float2*)(x + (size_t)(base + j) * DD + c);
      a0 = fmaf(w, xv.x, a0);
      a1 = fmaf(w, xv.y, a1);
    }
  }
  float* op = out + (size_t)g * DD + c;
  op[0] = a0;
  op[1] = a1;
}

extern "C" void kernel_launch(void* const* d_in, const int* in_sizes, int n_in,
                              void* d_out, int out_size, void* d_ws, size_t ws_size,
                              hipStream_t stream) {
  const float* x = (const float*)d_in[0];
  const void* seg = d_in[1];
  const float* W = (const float*)d_in[2];
  const float* b = (const float*)d_in[3];
  const float* q = (const float*)d_in[4];
  float* out = (float*)d_out;
  const int N = in_sizes[0] / DD;  // 131072

  unsigned char* Whl = (unsigned char*)d_ws;                 // 512 KB packed W (f16)
  float* sp0 = (float*)(Whl + 524288);                       // N partial scores (ny=0)
  float* sp1 = sp0 + N;                                      // N partial scores (ny=1)

  k_convert_w<<<128, 256, 0, stream>>>(W, Whl);
  dim3 grid(2, N / 128);                                     // x = ny fastest -> x-row cache reuse
  k_gemm_score<<<grid, 256, 0, stream>>>(x, Whl, b, q, sp0, N);
  k_softmax_out<<<NG, 256, 0, stream>>>(x, seg, sp0, sp1, out, N);
}

// Round 11
// 181.992 us; speedup vs baseline: 1.5470x; 1.0105x over previous
//
#include <hip/hip_runtime.h>

typedef _Float16 f16x8 __attribute__((ext_vector_type(8)));
typedef __fp16 fp16v2 __attribute__((ext_vector_type(2)));
typedef _Float16 f16v2 __attribute__((ext_vector_type(2)));
typedef short short8 __attribute__((ext_vector_type(8)));
typedef float f32x16 __attribute__((ext_vector_type(16)));

#define DD 512
#define NG 512

typedef __attribute__((address_space(3))) void lds_void;
typedef __attribute__((address_space(1))) void glb_void;

static __device__ __forceinline__ void gload_lds16(const void* g, void* l) {
  __builtin_amdgcn_global_load_lds((const glb_void*)g, (lds_void*)l, 16, 0, 0);
}

#define WAITV(n) asm volatile("s_waitcnt vmcnt(" #n ") lgkmcnt(0)" ::: "memory")
#define MEMFENCE asm volatile("" ::: "memory")

// packed f32x2 -> f16x2 (RTZ), bit-cast to _Float16 vector
static __device__ __forceinline__ f16v2 pk16(float a, float b) {
  fp16v2 p = __builtin_amdgcn_cvt_pkrtz(a, b);
  return __builtin_bit_cast(f16v2, p);
}

// fast tanh: 1 - 2/(e^{2v}+1), native exp/rcp (~1e-6 abs err, saturates correctly)
static __device__ __forceinline__ float fast_tanh(float v) {
  float e = __expf(2.0f * v);
  return 1.0f - 2.0f * __builtin_amdgcn_rcpf(e + 1.0f);
}

// Whl layout (f16, RTE): [ny(2)][kt(32)][ct(8)][lane(64)=khalf*32+c31][8 f16]
// One (ny,kt) slice = 8 KB contiguous -> staged linearly by global_load_lds.
// B-fragment ds_read is lds + lane*16 (+ct*1024): 64 lanes read 1024
// contiguous bytes -> zero bank conflicts (verified rounds 4/9).
__global__ __launch_bounds__(256) void k_convert_w(const float* __restrict__ W,
                                                   unsigned char* __restrict__ Whl) {
  int t = blockIdx.x * 256 + threadIdx.x;   // 32768 = 512 W-rows x 64 kgroups(8)
  int r512 = t >> 6, kg = t & 63;
  int ny = r512 >> 8, col = r512 & 255;
  int ct = col >> 5, c31 = col & 31;
  int kt = kg >> 1, khalf = kg & 1;
  const float* p = W + (size_t)r512 * DD + kg * 8;
  short8 h;
#pragma unroll
  for (int j = 0; j < 8; ++j) {
    _Float16 hh = (_Float16)p[j];              // RTE
    h[j] = (short)__builtin_bit_cast(unsigned short, hh);
  }
  unsigned char* dst = Whl + (size_t)ny * 262144 + (size_t)kt * 8192 +
                       ct * 1024 + (khalf * 32 + c31) * 16;
  *(short8*)dst = h;
}

// Fused GEMM(tanh-gate) + query-dot.  Wave = 32 rows x 128 cols (4 ct tiles x
// 1 f16 MFMA, acc = 64 AGPRs -> ~115 regs -> 4 waves/SIMD).  Block = 4 waves
// (2 rg x 2 cg) = 64 rows x 256 cols (ny = col half).  B slices (8 KB f16) +
// A x-tiles (4 KB f32, sigma-swizzled chunks) staged via global_load_lds
// ring-3, counted vmcnt (structure verified rounds 6-9).  37.4 KB LDS ->
// 4 blocks/CU at staggered phases: barrier stalls covered cross-block.
__global__ __launch_bounds__(256, 4) void k_gemm_score(
    const float* __restrict__ x, const unsigned char* __restrict__ Whl,
    const float* __restrict__ bias, const float* __restrict__ query,
    float* __restrict__ score_part, int N) {
  __shared__ unsigned char ldsB[3][8192];
  __shared__ unsigned char ldsA[3][4096];
  __shared__ float comb[2][64];
  const int tid = threadIdx.x;
  const int wave = tid >> 6;
  const int lane = tid & 63;
  const int l31 = lane & 31;
  const int kh = lane >> 5;          // k-half within fragment
  const int rg = wave >> 1;          // row-group (0,1): rows rg*32..rg*32+31
  const int cg = wave & 1;           // col-group (0,1): cts cg*4..cg*4+3
  const int ny = blockIdx.x;
  const int brow0 = blockIdx.y * 64;

  const unsigned char* wsrc = Whl + (size_t)ny * 262144 +
                              (size_t)wave * 2048 + (size_t)lane * 16;

  // A staging: 256 chunks of 16B per slice; LDS[c] <- x-data[sigma(c)],
  // sigma(c) = c ^ ((c>>3)&7) (involution).  Chunk d: row = d>>2, kq = d&3.
  const int c0 = wave * 64 + lane;
  const int s0c = c0 ^ ((c0 >> 3) & 7);
  const float* asrc0 = x + (size_t)(brow0 + (s0c >> 2)) * DD + (s0c & 3) * 4;

  // A read offsets (bytes): logical chunk u = row*4 + 2*kh, row = rg*32+l31
  int aoff0, aoff1;
  {
    const int row = rg * 32 + l31;
    const int u = row * 4 + 2 * kh;
    const int m = (u >> 3) & 7;
    aoff0 = (u ^ m) * 16;
    aoff1 = ((u + 1) ^ m) * 16;
  }

  f32x16 acc[4];
#pragma unroll
  for (int j = 0; j < 4; ++j)
#pragma unroll
    for (int r = 0; r < 16; ++r) acc[j][r] = 0.f;

  // prologue: stage slices 0 and 1 (3 gloads each per wave: 2 B + 1 A)
#pragma unroll
  for (int s = 0; s < 2; ++s) {
#pragma unroll
    for (int i = 0; i < 2; ++i)
      gload_lds16(wsrc + (size_t)s * 8192 + i * 1024, &ldsB[s][wave * 2048 + i * 1024]);
    gload_lds16(asrc0 + s * 16, &ldsA[s][wave * 1024]);
    MEMFENCE;
  }

  for (int kt = 0; kt < 32; ++kt) {
    // slice kt's 3 gloads have exactly {kt+1}'s 3 newer -> vmcnt(3); tail drains.
    if (kt == 31) WAITV(0); else WAITV(3);
    __builtin_amdgcn_s_barrier();
    MEMFENCE;

    if (kt < 30) {  // stage slice kt+2 into slot (kt+2)%3 (readers of kt-1 done)
      const int s = (kt + 2) % 3;
      const unsigned char* src = wsrc + (size_t)(kt + 2) * 8192;
#pragma unroll
      for (int i = 0; i < 2; ++i)
        gload_lds16(src + i * 1024, &ldsB[s][wave * 2048 + i * 1024]);
      gload_lds16(asrc0 + (kt + 2) * 16, &ldsA[s][wave * 1024]);
    }
    MEMFENCE;

    const int slot = kt % 3;
    const unsigned char* ab = &ldsA[slot][0];
    const unsigned char* bb = &ldsB[slot][lane * 16 + cg * 4096];

    // A fragment: packed RTZ f32->f16 (4 v_cvt_pkrtz instead of 8 scalar cvt)
    const float4 a0 = *(const float4*)(ab + aoff0);
    const float4 a1 = *(const float4*)(ab + aoff1);
    f16x8 ah;
    {
      f16v2 p;
      p = pk16(a0.x, a0.y); ah[0] = p[0]; ah[1] = p[1];
      p = pk16(a0.z, a0.w); ah[2] = p[0]; ah[3] = p[1];
      p = pk16(a1.x, a1.y); ah[4] = p[0]; ah[5] = p[1];
      p = pk16(a1.z, a1.w); ah[6] = p[0]; ah[7] = p[1];
    }

    __builtin_amdgcn_s_setprio(1);
#pragma unroll
    for (int j = 0; j < 4; ++j) {
      f16x8 bh = *(const f16x8*)(bb + j * 1024);
      acc[j] = __builtin_amdgcn_mfma_f32_32x32x16_f16(ah, bh, acc[j], 0, 0, 0);
    }
    __builtin_amdgcn_s_setprio(0);
  }

  // epilogue: tanh + query-dot; reduce over the 32 col-lanes; combine cg halves
  float sp[16];
#pragma unroll
  for (int r = 0; r < 16; ++r) sp[r] = 0.f;
#pragma unroll
  for (int j = 0; j < 4; ++j) {
    const int col = ny * 256 + (cg * 4 + j) * 32 + l31;
    const float bb2 = bias[col];
    const float qq = query[col];
#pragma unroll
    for (int r = 0; r < 16; ++r)
      sp[r] += fast_tanh(acc[j][r] + bb2) * qq;
  }
  __syncthreads();
#pragma unroll
  for (int r = 0; r < 16; ++r) {
    float v = sp[r];
    v += __shfl_xor(v, 1);
    v += __shfl_xor(v, 2);
    v += __shfl_xor(v, 4);
    v += __shfl_xor(v, 8);
    v += __shfl_xor(v, 16);
    if (l31 == 0)  // C row = (r&3) + 8*(r>>2) + 4*kh  (m74/m101 layout)
      comb[cg][rg * 32 + (r & 3) + 8 * (r >> 2) + 4 * kh] = v;
  }
  __syncthreads();
  if (tid < 64)
    score_part[(size_t)ny * N + brow0 + tid] = comb[0][tid] + comb[1][tid];
}

// Per-graph: segmented softmax over (sp0+sp1) + weighted sum of x rows -> out[g][512]
__global__ __launch_bounds__(256) void k_softmax_out(
    const float* __restrict__ x, const void* __restrict__ segp,
    const float* __restrict__ sp0, const float* __restrict__ sp1,
    float* __restrict__ out, int N) {
  const int g = blockIdx.x;
  const int tid = threadIdx.x;

  // dtype probe: int64 element N/2-1 is a graph id (<NG) iff buffer is int64.
  const long long probe = ((const long long*)segp)[N / 2 - 1];
  const bool is64 = ((unsigned long long)probe < (unsigned long long)NG);
  const long long* s64 = (const long long*)segp;
  const int* s32 = (const int*)segp;

  int s0, s1;
  {
    int lo = 0, hi = N;
    while (lo < hi) {
      int m = (lo + hi) >> 1;
      long long v = is64 ? s64[m] : (long long)s32[m];
      if (v < (long long)g) lo = m + 1; else hi = m;
    }
    s0 = lo;
    lo = s0; hi = N;
    while (lo < hi) {
      int m = (lo + hi) >> 1;
      long long v = is64 ? s64[m] : (long long)s32[m];
      if (v < (long long)(g + 1)) lo = m + 1; else hi = m;
    }
    s1 = lo;
  }

  __shared__ float red[4];
  __shared__ float wbuf[512];

  float lm = -INFINITY;
  for (int i = s0 + tid; i < s1; i += 256) lm = fmaxf(lm, sp0[i] + sp1[i]);
#pragma unroll
  for (int m = 1; m < 64; m <<= 1) lm = fmaxf(lm, __shfl_xor(lm, m));
  if ((tid & 63) == 0) red[tid >> 6] = lm;
  __syncthreads();
  const float mx = fmaxf(fmaxf(red[0], red[1]), fmaxf(red[2], red[3]));
  __syncthreads();

  float ls = 0.f;
  for (int i = s0 + tid; i < s1; i += 256) ls += expf(sp0[i] + sp1[i] - mx);
#pragma unroll
  for (int m = 1; m < 64; m <<= 1) ls += __shfl_xor(ls, m);
  if ((tid & 63) == 0) red[tid >> 6] = ls;
  __syncthreads();
  const float sum = red[0] + red[1] + red[2] + red[3];
  const float inv = sum > 0.f ? 1.0f / sum : 0.f;

  float a0 = 0.f, a1 = 0.f;
  const int c = tid * 2;
  for (int base = s0; base < s1; base += 512) {
    const int cnt = min(512, s1 - base);
    __syncthreads();
    for (int i = tid; i < cnt; i += 256)
      wbuf[i] = expf(sp0[base + i] + sp1[base + i] - mx) * inv;
    __syncthreads();
#pragma unroll 4
    for (int j = 0; j < cnt; ++j) {
      const float w = wbuf[j];
      const float2 xv = *(const float2*)(x + (size_t)(base + j) * DD + c);
      a0 = fmaf(w, xv.x, a0);
      a1 = fmaf(w, xv.y, a1);
    }
  }
  float* op = out + (size_t)g * DD + c;
  op[0] = a0;
  op[1] = a1;
}

extern "C" void kernel_launch(void* const* d_in, const int* in_sizes, int n_in,
                              void* d_out, int out_size, void* d_ws, size_t ws_size,
                              hipStream_t stream) {
  const float* x = (const float*)d_in[0];
  const void* seg = d_in[1];
  const float* W = (const float*)d_in[2];
  const float* b = (const float*)d_in[3];
  const float* q = (const float*)d_in[4];
  float* out = (float*)d_out;
  const int N = in_sizes[0] / DD;  // 131072

  unsigned char* Whl = (unsigned char*)d_ws;                 // 512 KB packed W (f16)
  float* sp0 = (float*)(Whl + 524288);                       // N partial scores (ny=0)
  float* sp1 = sp0 + N;                                      // N partial scores (ny=1)

  k_convert_w<<<128, 256, 0, stream>>>(W, Whl);
  dim3 grid(2, N / 64);                                      // x = ny fastest -> x-row cache reuse
  k_gemm_score<<<grid, 256, 0, stream>>>(x, Whl, b, q, sp0, N);
  k_softmax_out<<<NG, 256, 0, stream>>>(x, seg, sp0, sp1, out, N);
}